// Round 6
// baseline (449.846 us; speedup 1.0000x reference)
//
#include <hip/hip_runtime.h>

// ---------------------------------------------------------------------------
// SubtitleColorConsistencyLoss — MI355X  (v4)
// Inputs: color f32 [8,32,512,512], gt f32 [8,1,512,512],
//         binary f32 [8,1,512,512], labels i32 [8,512,512] -> scalar f32.
//
// v4: two-pass structure to maximize streaming BW on the 256 MB color read.
//   A: per (n, 1024-px chunk): read masks once, write 1 B/px seg-code +
//      per-chunk label-mask byte to d_ws; accumulate region/comp counts.
//   B: per (n, chunk, 8-channel group): stage 1 KB codes in LDS, each wave
//      processes its channel-pair ONCE (no sequential multi-pass, 1 butterfly
//      tail), single-label fast path from the chunk's label byte (general
//      fallback loop for multi-label chunks), atomics straight to ws stats.
//   final: 1-wave epilogue (unchanged, verified absmax=0).
// d_ws layout (bytes): [0..9728) stats f32[8][304]; [12288..14336) lc bytes;
//                      [16384..16384+2MB) codes u32.
// ---------------------------------------------------------------------------

#define NIMG   8
#define NCH    32
#define IMHW   (512 * 512)
#define CHUNK  1024                 // pixels per chunk (2 rows)
#define CPI    (IMHW / CHUNK)       // 256 chunks per image
#define WSN    304                  // floats per image in stats
// stats layout (per image, float offsets):
//   0 sub_sum[32] | 32 scene_sum[32] | 64 vtot_sum[32] | 96 compsum[6][32]
//   288 sub_cnt | 289 scene_cnt | 291 compcnt[6] | 297 comps2[6]
#define LC_OFF    12288
#define CODES_OFF 16384

__device__ __forceinline__ float redhalf(float x) {
    x += __shfl_xor(x, 1);  x += __shfl_xor(x, 2);  x += __shfl_xor(x, 4);
    x += __shfl_xor(x, 8);  x += __shfl_xor(x, 16);
    return x;
}
__device__ __forceinline__ float red64(float x) {
    x = redhalf(x); x += __shfl_xor(x, 32); return x;
}

// ---- kernel A: codes + counts + per-chunk labelmask ----
__global__ __launch_bounds__(256) void scl_codes(
    const float* __restrict__ gt, const float* __restrict__ bin,
    const int* __restrict__ lab, float* __restrict__ ws,
    unsigned char* __restrict__ lc, unsigned* __restrict__ codes)
{
    __shared__ float ldsc[8];      // sub, scene, comp[6]
    __shared__ int labmask;
    const int tid = threadIdx.x;
    if (tid < 8) ldsc[tid] = 0.f;
    if (tid == 0) labmask = 0;

    const int n = blockIdx.x / CPI;
    const int q = blockIdx.x % CPI;
    const int base = n * IMHW + q * CHUNK;
    const int p = base + (tid << 2);

    const float4 g4 = *reinterpret_cast<const float4*>(gt + p);
    const float4 b4 = *reinterpret_cast<const float4*>(bin + p);
    const int4   l4 = *reinterpret_cast<const int4*>(lab + p);
    const float gg[4] = {g4.x, g4.y, g4.z, g4.w};
    const float bb[4] = {b4.x, b4.y, b4.z, b4.w};
    const int   ll[4] = {l4.x, l4.y, l4.z, l4.w};

    unsigned wrd = 0; int lm = 0;
    float c0 = 0.f, c1 = 0.f;
    float ck[6] = {0.f, 0.f, 0.f, 0.f, 0.f, 0.f};
#pragma unroll
    for (int e = 0; e < 4; ++e) {
        const bool sub  = gg[e] > 0.5f;
        const bool text = bb[e] > 0.5f;
        const int  r    = sub ? 0 : (text ? 1 : 2);   // 0=sub 1=scene 2=bg
        unsigned   ul   = (unsigned)ll[e];            // labels 0..6 expected
        if (ul > 7u) ul = 7u;                         // clamp bogus -> "other"
        wrd |= ((ul << 2) | (unsigned)r) << (8 * e);
        lm  |= 1 << ul;
        c0  += (r == 0) ? 1.f : 0.f;
        c1  += (r == 1) ? 1.f : 0.f;
#pragma unroll
        for (int kk = 0; kk < 6; ++kk)
            ck[kk] += (ul == (unsigned)(kk + 1)) ? 1.f : 0.f;
    }
    codes[(base >> 2) + tid] = wrd;

    c0 = red64(c0); c1 = red64(c1);
#pragma unroll
    for (int kk = 0; kk < 6; ++kk) ck[kk] = red64(ck[kk]);
    lm |= __shfl_xor(lm, 1);  lm |= __shfl_xor(lm, 2);  lm |= __shfl_xor(lm, 4);
    lm |= __shfl_xor(lm, 8);  lm |= __shfl_xor(lm, 16); lm |= __shfl_xor(lm, 32);

    __syncthreads();                       // ldsc/labmask init visible
    if ((tid & 63) == 0) {
        atomicAdd(&ldsc[0], c0);
        atomicAdd(&ldsc[1], c1);
#pragma unroll
        for (int kk = 0; kk < 6; ++kk) atomicAdd(&ldsc[2 + kk], ck[kk]);
        atomicOr(&labmask, lm);
    }
    __syncthreads();

    float* wsn = ws + (size_t)n * WSN;
    if (tid == 0) {
        lc[n * CPI + q] = (unsigned char)((labmask >> 1) & 0x3F);  // bits: labels 1..6
        atomicAdd(&wsn[288], ldsc[0]);
        atomicAdd(&wsn[289], ldsc[1]);
    }
    if (tid >= 2 && tid < 8) atomicAdd(&wsn[291 + (tid - 2)], ldsc[tid]);
}

// ---- kernel B: color streaming sums ----
__global__ __launch_bounds__(256) void scl_color(
    const float* __restrict__ color, const float* __restrict__ ws_ro,
    const unsigned char* __restrict__ lc, const unsigned* __restrict__ codes,
    float* __restrict__ ws)
{
    __shared__ unsigned ldsC[CHUNK / 4];   // 1 KB of codes for this chunk
    (void)ws_ro;

    const int bid = blockIdx.x;            // = ((n*CPI)+q)*4 + g
    const int g = bid & 3;
    const int q = (bid >> 2) & (CPI - 1);
    const int n = bid >> 10;

    const int tid  = threadIdx.x;
    const int lane = tid & 63;
    const int wv   = tid >> 6;
    const int half = lane >> 5;
    const int l32  = lane & 31;

    const int base = n * IMHW + q * CHUNK;
    ldsC[tid] = codes[(base >> 2) + tid];

    const unsigned mask6 = lc[n * CPI + q];            // labels present (1..6)
    const int Lc = mask6 ? __ffs(mask6) : 255;         // __ffs is 1-based = label id

    const int c = g * 8 + wv * 2 + half;               // this lane's channel
    const float* colc = color + ((size_t)n * NCH + c) * IMHW + q * CHUNK;

    __syncthreads();                                   // codes staged

    float vt = 0.f, s0 = 0.f, s1 = 0.f, aL = 0.f, s2 = 0.f;
#pragma unroll
    for (int j = 0; j < CHUNK; j += 128) {
        const int off = j + (l32 << 2);
        const float4 v4 = *reinterpret_cast<const float4*>(colc + off);
        const unsigned cw = ldsC[off >> 2];   // 32 consecutive words/half; halves broadcast
        const float vv[4] = {v4.x, v4.y, v4.z, v4.w};
#pragma unroll
        for (int e = 0; e < 4; ++e) {
            const float v = vv[e];
            const int r = (int)((cw >> (8 * e)) & 3u);
            const int l = (int)((cw >> (8 * e + 2)) & 0x3Fu);
            vt += v;
            s0 += (r == 0) ? v : 0.f;
            s1 += (r == 1) ? v : 0.f;
            const float mv = (l == Lc) ? v : 0.f;
            aL += mv;
            s2 = fmaf(mv, mv, s2);
        }
    }

    vt = redhalf(vt); s0 = redhalf(s0); s1 = redhalf(s1);
    aL = redhalf(aL); s2 = redhalf(s2);
    s2 += __shfl_xor(s2, 32);              // both channels' |f|^2 combined

    float* wsn = ws + (size_t)n * WSN;
    if (l32 == 0) {                        // lane 0 (c even) and lane 32 (c odd)
        atomicAdd(&wsn[ 0 + c], s0);
        atomicAdd(&wsn[32 + c], s1);
        atomicAdd(&wsn[64 + c], vt);
        if (Lc >= 1 && Lc <= 6) {
            atomicAdd(&wsn[96 + (Lc - 1) * 32 + c], aL);
            if (lane == 0) atomicAdd(&wsn[297 + (Lc - 1)], s2);
        }
    }

    // general-data fallback: extra labels in this chunk (uniform; not taken
    // on 2-row chunks of the rect-component generator)
    unsigned extra = mask6 ? (mask6 & (mask6 - 1)) : 0u;
    while (extra) {
        const int L2 = __ffs(extra); extra &= extra - 1;
        float aX = 0.f, sX = 0.f;
#pragma unroll
        for (int j = 0; j < CHUNK; j += 128) {
            const int off = j + (l32 << 2);
            const float4 v4 = *reinterpret_cast<const float4*>(colc + off);
            const unsigned cw = ldsC[off >> 2];
            const float vv[4] = {v4.x, v4.y, v4.z, v4.w};
#pragma unroll
            for (int e = 0; e < 4; ++e) {
                const int l = (int)((cw >> (8 * e + 2)) & 0x3Fu);
                const float mv = (l == L2) ? vv[e] : 0.f;
                aX += mv;
                sX = fmaf(mv, mv, sX);
            }
        }
        aX = redhalf(aX); sX = redhalf(sX);
        sX += __shfl_xor(sX, 32);
        if (l32 == 0 && L2 >= 1 && L2 <= 6) {
            atomicAdd(&wsn[96 + (L2 - 1) * 32 + c], aX);
            if (lane == 0) atomicAdd(&wsn[297 + (L2 - 1)], sX);
        }
    }
}

// ---- finalize: unchanged from v3 (verified absmax = 0) ----
__global__ void scl_final(const float* __restrict__ ws, float* __restrict__ out)
{
    const int lane = threadIdx.x;               // blockDim = 64 (one wave)
    const int n = lane / 6;
    const int k = lane - n * 6;
    const bool active = lane < 48;              // 8 images x 6 components

    float t_cv = 0.f, t_intra = 0.f, t_inter = 0.f, t_inst = 0.f, t_instn = 0.f;
    float t_sbg = 0.f, t_sbgn = 0.f, t_ssc = 0.f, t_sscn = 0.f;

    if (active) {
        const float* w = ws + (size_t)n * WSN;
        const float cnt    = w[291 + k];
        const float s2     = w[297 + k];
        const float subc   = w[288];
        const float scenec = w[289];
        const float bgc    = 262144.f - subc - scenec;   // exact (ints < 2^24)

        float nv = 0.f;
#pragma unroll
        for (int kk = 0; kk < 6; ++kk) nv += (w[291 + kk] >= 20.f) ? 1.f : 0.f;

        const bool comp_big   = cnt >= 20.f;
        const bool item_valid = (bgc >= 20.f) && (nv >= 1.f);
        const bool cv         = comp_big && item_valid;

        const float den  = cnt + 1e-6f;
        const float dsub = subc + 1e-6f;
        const float dbg  = bgc + 1e-6f;
        const float dsc  = scenec + 1e-6f;

        float dot_mS1 = 0.f, dot_mm = 0.f, d2bg = 0.f, d2sub = 0.f;
        for (int c = 0; c < 32; ++c) {
            const float S1 = w[96 + k * 32 + c];
            const float m  = S1 / den;
            dot_mS1 = fmaf(m, S1, dot_mS1);
            dot_mm  = fmaf(m, m, dot_mm);
            const float msub = w[c] / dsub;
            const float mbg  = (w[64 + c] - w[c] - w[32 + c]) / dbg;  // bg = vtot-sub-scene
            float d = m - mbg;  d2bg  = fmaf(d, d, d2bg);
            d = m - msub;       d2sub = fmaf(d, d, d2sub);
        }
        const float intra_k = (s2 - 2.f * dot_mS1 + cnt * dot_mm) / den;

        if (cv) {
            t_cv = 1.f;
            t_intra = intra_k;
            const float dd = sqrtf(fmaxf(d2bg, 1e-12f));
            const float r  = fmaxf(0.5f - dd, 0.f);
            t_inter = r * r;
        }
        const bool multi = item_valid && (nv > 1.f);
        if (cv && multi) t_inst = d2sub;

        if (k == 0) {                            // per-image terms, once
            if (multi) t_instn = nv;
            const bool bgcond = item_valid && (subc >= 20.f);
            const bool sccond = item_valid && (scenec >= 20.f) && (subc >= 20.f);
            float d2sb = 0.f, d2ss = 0.f;
            for (int c = 0; c < 32; ++c) {
                const float msub = w[c] / dsub;
                const float mbg  = (w[64 + c] - w[c] - w[32 + c]) / dbg;
                const float msc  = w[32 + c] / dsc;
                float a = msub - mbg; d2sb = fmaf(a, a, d2sb);
                float b = msub - msc; d2ss = fmaf(b, b, d2ss);
            }
            if (bgcond) {
                const float dd = sqrtf(fmaxf(d2sb, 1e-12f));
                const float r  = fmaxf(0.5f - dd, 0.f);
                t_sbg = r * r; t_sbgn = 1.f;
            }
            if (sccond) {
                const float dd = sqrtf(fmaxf(d2ss, 1e-12f));
                const float r  = fmaxf(1.0f - dd, 0.f);   // 2*MARGIN
                t_ssc = r * r; t_sscn = 1.f;
            }
        }
    }

#define RED64(x) { x += __shfl_xor(x, 1); x += __shfl_xor(x, 2); x += __shfl_xor(x, 4); \
                   x += __shfl_xor(x, 8); x += __shfl_xor(x, 16); x += __shfl_xor(x, 32); }
    RED64(t_cv) RED64(t_intra) RED64(t_inter) RED64(t_inst) RED64(t_instn)
    RED64(t_sbg) RED64(t_sbgn) RED64(t_ssc) RED64(t_sscn)
#undef RED64

    if (lane == 0) {
        const float total = t_cv;
        auto avg = [](float s, float nn) { return nn > 0.f ? s / fmaxf(nn, 1.f) : 0.f; };
        const float loss = avg(t_intra, total)
                         + 0.4f * avg(t_inter, total)
                         + 0.1f * avg(t_inst, t_instn)
                         + 0.2f * avg(t_sbg, t_sbgn)
                         + 0.5f * avg(t_ssc, t_sscn);
        out[0] = (total > 0.f) ? loss : 0.f;
    }
}

extern "C" void kernel_launch(void* const* d_in, const int* in_sizes, int n_in,
                              void* d_out, int out_size, void* d_ws, size_t ws_size,
                              hipStream_t stream)
{
    (void)in_sizes; (void)n_in; (void)out_size; (void)ws_size;
    const float* color = (const float*)d_in[0];
    const float* gt    = (const float*)d_in[1];
    const float* bin   = (const float*)d_in[2];
    const int*   lab   = (const int*)d_in[3];
    float*          ws    = (float*)d_ws;
    unsigned char*  lc    = (unsigned char*)d_ws + LC_OFF;
    unsigned*       codes = (unsigned*)((char*)d_ws + CODES_OFF);
    float* out = (float*)d_out;

    hipMemsetAsync(ws, 0, (size_t)NIMG * WSN * sizeof(float), stream);
    hipLaunchKernelGGL(scl_codes, dim3(NIMG * CPI), dim3(256), 0, stream,
                       gt, bin, lab, ws, lc, codes);
    hipLaunchKernelGGL(scl_color, dim3(NIMG * CPI * 4), dim3(256), 0, stream,
                       color, ws, lc, codes, ws);
    hipLaunchKernelGGL(scl_final, dim3(1), dim3(64), 0, stream, ws, out);
}

// Round 7
// 434.807 us; speedup vs baseline: 1.0346x; 1.0346x over previous
//
#include <hip/hip_runtime.h>

// ---------------------------------------------------------------------------
// SubtitleColorConsistencyLoss — MI355X  (v5: atomic-free hot path)
// Inputs: color f32 [8,32,512,512], gt f32 [8,1,512,512],
//         binary f32 [8,1,512,512], labels i32 [8,512,512] -> scalar f32.
//
// Theory being tested: v2-v4 all bottlenecked (~1.6 TB/s streaming) on
// contended device-scope atomicAdds (~300-deep same-address chains at the
// coherence point), NOT on the streaming itself (harness fills hit 6.7 TB/s).
// v5: main kernel writes per-block partials to UNIQUE slots (plain stores);
// tiny reduce kernel folds 128 partials/image into the 304-float stats.
// d_ws: [0..9728) stats f32[8][304] | [16384..) partials f32[1024][144].
// ---------------------------------------------------------------------------

#define NIMG   8
#define NCH    32
#define IMHW   (512 * 512)
#define STRIPE 2048                 // pixels per block (4 rows)
#define BPI    (IMHW / STRIPE)      // 128 blocks per image
#define WSN    304                  // floats per image in stats
// stats layout (per image, float offsets):
//   0 sub_sum[32] | 32 scene_sum[32] | 64 vtot_sum[32] | 96 compsum[6][32]
//   288 sub_cnt | 289 scene_cnt | 291 compcnt[6] | 297 comps2[6]
#define PBS    144                  // floats per block-partial
// partial layout: 0 sub[32] | 32 scene[32] | 64 vtot[32] | 96 aL[32]
//                 128 {s2, c0, c1, cntL, Lcf}
#define PB_OFF 16384                // byte offset of partials in d_ws

__device__ __forceinline__ float redhalf(float x) {
    x += __shfl_xor(x, 1);  x += __shfl_xor(x, 2);  x += __shfl_xor(x, 4);
    x += __shfl_xor(x, 8);  x += __shfl_xor(x, 16);
    return x;
}
__device__ __forceinline__ float red64(float x) {
    x = redhalf(x); x += __shfl_xor(x, 32); return x;
}

__global__ __launch_bounds__(256) void scl_main(
    const float* __restrict__ color, const float* __restrict__ gt,
    const float* __restrict__ bin, const int* __restrict__ lab,
    float* __restrict__ stats, float* __restrict__ pb)
{
    __shared__ unsigned codes[STRIPE / 4];   // 2 KB, 1 B/px
    __shared__ float s2buf[16];
    __shared__ float cnts[2];                // sub_cnt, scene_cnt
    __shared__ float cnt6[6];                // per-label pixel counts
    __shared__ int labmask;

    const int tid = threadIdx.x;
    if (tid < 2) cnts[tid] = 0.f;
    if (tid < 6) cnt6[tid] = 0.f;
    if (tid == 0) labmask = 0;

    const int n    = blockIdx.x / BPI;
    const int blk  = blockIdx.x % BPI;
    const int pix0 = blk * STRIPE;

    const float* gtn  = gt  + (size_t)n * IMHW;
    const float* binn = bin + (size_t)n * IMHW;
    const int*   labn = lab + (size_t)n * IMHW;
    const float* coln = color + (size_t)n * NCH * IMHW;

    // ---- phase 1: codes + per-thread counts (each pixel exactly once) ----
    float c0 = 0.f, c1 = 0.f;
    float ck[6] = {0.f, 0.f, 0.f, 0.f, 0.f, 0.f};
    int lm = 0;
#pragma unroll
    for (int jj = 0; jj < 2; ++jj) {
        const int off = jj * 1024 + (tid << 2);
        const int p   = pix0 + off;
        const float4 g4 = *reinterpret_cast<const float4*>(gtn + p);
        const float4 b4 = *reinterpret_cast<const float4*>(binn + p);
        const int4   l4 = *reinterpret_cast<const int4*>(labn + p);
        const float gg[4] = {g4.x, g4.y, g4.z, g4.w};
        const float bb[4] = {b4.x, b4.y, b4.z, b4.w};
        const int   ll[4] = {l4.x, l4.y, l4.z, l4.w};
        unsigned wrd = 0;
#pragma unroll
        for (int e = 0; e < 4; ++e) {
            const bool sub  = gg[e] > 0.5f;
            const bool text = bb[e] > 0.5f;
            const int  r    = sub ? 0 : (text ? 1 : 2);  // 0=sub 1=scene 2=bg
            unsigned   ul   = (unsigned)ll[e];
            if (ul > 7u) ul = 7u;                        // clamp bogus labels
            wrd |= ((ul << 2) | (unsigned)r) << (8 * e);
            lm  |= 1 << ul;
            c0  += (r == 0) ? 1.f : 0.f;
            c1  += (r == 1) ? 1.f : 0.f;
#pragma unroll
            for (int kk = 0; kk < 6; ++kk)
                ck[kk] += (ul == (unsigned)(kk + 1)) ? 1.f : 0.f;
        }
        codes[off >> 2] = wrd;
    }
    __syncthreads();                 // codes + zeroed LDS counters visible

    c0 = red64(c0); c1 = red64(c1);
#pragma unroll
    for (int kk = 0; kk < 6; ++kk) ck[kk] = red64(ck[kk]);
    lm |= __shfl_xor(lm, 1);  lm |= __shfl_xor(lm, 2);  lm |= __shfl_xor(lm, 4);
    lm |= __shfl_xor(lm, 8);  lm |= __shfl_xor(lm, 16); lm |= __shfl_xor(lm, 32);
    if ((tid & 63) == 0) {           // one LDS-atomic set per wave
        atomicAdd(&cnts[0], c0);
        atomicAdd(&cnts[1], c1);
#pragma unroll
        for (int kk = 0; kk < 6; ++kk) atomicAdd(&cnt6[kk], ck[kk]);
        atomicOr(&labmask, lm);
    }
    __syncthreads();                 // counts + labmask final

    const unsigned cmask = (((unsigned)labmask) >> 1) & 0x3Fu;  // labels 1..6
    const int Lc = cmask ? __ffs(cmask) : 255;                  // label id

    // ---- phase 2: color streaming, 4-batched loads, plain stores ----
    const int lane = tid & 63;
    const int wv   = tid >> 6;
    const int half = lane >> 5;
    const int l32  = lane & 31;
    float* pbb = pb + (size_t)blockIdx.x * PBS;

    for (int cpi = 0; cpi < 4; ++cpi) {
        const int cp = wv * 4 + cpi;          // channel pair (wave-uniform)
        const int c  = cp * 2 + half;
        const float* colc = coln + (size_t)c * IMHW + pix0;

        float vt = 0.f, s0 = 0.f, s1 = 0.f, aL = 0.f, s2 = 0.f;
#pragma unroll
        for (int j0 = 0; j0 < STRIPE; j0 += 512) {
            float4 a0, a1, a2, a3;            // 4 independent loads in flight
            unsigned w0, w1, w2, w3;
            {
                const int o0 = j0 + 0 * 128 + (l32 << 2);
                const int o1 = j0 + 1 * 128 + (l32 << 2);
                const int o2 = j0 + 2 * 128 + (l32 << 2);
                const int o3 = j0 + 3 * 128 + (l32 << 2);
                a0 = *reinterpret_cast<const float4*>(colc + o0);
                a1 = *reinterpret_cast<const float4*>(colc + o1);
                a2 = *reinterpret_cast<const float4*>(colc + o2);
                a3 = *reinterpret_cast<const float4*>(colc + o3);
                w0 = codes[o0 >> 2]; w1 = codes[o1 >> 2];
                w2 = codes[o2 >> 2]; w3 = codes[o3 >> 2];
            }
#define PROC(A, W) { \
            const float vv[4] = {A.x, A.y, A.z, A.w}; \
            _Pragma("unroll") \
            for (int e = 0; e < 4; ++e) { \
                const float v = vv[e]; \
                const int r = (int)((W >> (8 * e)) & 3u); \
                const int l = (int)((W >> (8 * e + 2)) & 0x3Fu); \
                vt += v; \
                s0 += (r == 0) ? v : 0.f; \
                s1 += (r == 1) ? v : 0.f; \
                const float mv = (l == Lc) ? v : 0.f; \
                aL += mv; \
                s2 = fmaf(mv, mv, s2); \
            } }
            PROC(a0, w0) PROC(a1, w1) PROC(a2, w2) PROC(a3, w3)
#undef PROC
        }

        vt = redhalf(vt); s0 = redhalf(s0); s1 = redhalf(s1);
        aL = redhalf(aL); s2 = redhalf(s2);
        s2 += __shfl_xor(s2, 32);             // both channels of the pair

        if (l32 == 0) {                       // lane 0 (c even) / lane 32 (c odd)
            pbb[ 0 + c] = s0;
            pbb[32 + c] = s1;
            pbb[64 + c] = vt;
            pbb[96 + c] = aL;
            if (lane == 0) s2buf[cp] = s2;
        }
    }
    __syncthreads();                          // s2buf complete

    if (tid == 0) {
        float s2t = 0.f;
#pragma unroll
        for (int i = 0; i < 16; ++i) s2t += s2buf[i];
        pbb[128] = s2t;
        pbb[129] = cnts[0];
        pbb[130] = cnts[1];
        pbb[131] = (Lc >= 1 && Lc <= 6) ? cnt6[Lc - 1] : 0.f;
        pbb[132] = (float)Lc;
    }

    // general-data fallback: extra labels in this stripe (uniform loop; never
    // taken with rect components >= 35 rows apart vs 4-row stripes)
    unsigned extra = cmask ? (cmask & (cmask - 1)) : 0u;
    if (extra && tid == 0) {
        unsigned ex = extra;
        while (ex) {
            const int L2 = __ffs(ex); ex &= ex - 1;
            atomicAdd(&stats[(size_t)n * WSN + 291 + (L2 - 1)], cnt6[L2 - 1]);
        }
    }
    while (extra) {
        const int L2 = __ffs(extra); extra &= extra - 1;
        for (int cpi = 0; cpi < 4; ++cpi) {
            const int cp = wv * 4 + cpi;
            const int c  = cp * 2 + half;
            const float* colc = coln + (size_t)c * IMHW + pix0;
            float aX = 0.f, sX = 0.f;
            for (int j = 0; j < STRIPE; j += 128) {
                const int off = j + (l32 << 2);
                const float4 v4 = *reinterpret_cast<const float4*>(colc + off);
                const unsigned cw = codes[off >> 2];
                const float vv[4] = {v4.x, v4.y, v4.z, v4.w};
#pragma unroll
                for (int e = 0; e < 4; ++e) {
                    const int l = (int)((cw >> (8 * e + 2)) & 0x3Fu);
                    const float mv = (l == L2) ? vv[e] : 0.f;
                    aX += mv;
                    sX = fmaf(mv, mv, sX);
                }
            }
            aX = redhalf(aX); sX = redhalf(sX);
            sX += __shfl_xor(sX, 32);
            if (l32 == 0) {
                atomicAdd(&stats[(size_t)n * WSN + 96 + (L2 - 1) * 32 + c], aX);
                if (lane == 0)
                    atomicAdd(&stats[(size_t)n * WSN + 297 + (L2 - 1)], sX);
            }
        }
    }
}

// ---- reduce: fold 128 block-partials per image into stats (no glb atomics,
//      += coexists with prior kernel's rare fallback atomics) ----
__global__ __launch_bounds__(256) void scl_reduce(
    const float* __restrict__ pb, float* __restrict__ stats)
{
    __shared__ float comp[6][32];
    __shared__ float comps2[6];
    __shared__ float compcnt[6];

    const int tid = threadIdx.x;
    const int n   = blockIdx.x;
    if (tid < 192) (&comp[0][0])[tid] = 0.f;
    if (tid < 6) { comps2[tid] = 0.f; compcnt[tid] = 0.f; }
    __syncthreads();

    const float* base = pb + (size_t)n * BPI * PBS;
    float* w = stats + (size_t)n * WSN;

    if (tid < 96) {                          // sub / scene / vtot rows
        const int c = tid & 31, row = tid >> 5;
        float acc = 0.f;
#pragma unroll 4
        for (int q = 0; q < BPI; ++q) acc += base[q * PBS + row * 32 + c];
        w[row * 32 + c] += acc;
    } else if (tid < 128) {                  // aL scatter by chunk label
        const int c = tid - 96;
#pragma unroll 4
        for (int q = 0; q < BPI; ++q) {
            const float a = base[q * PBS + 96 + c];
            const int   L = (int)base[q * PBS + 132];
            if (L >= 1 && L <= 6) atomicAdd(&comp[L - 1][c], a);
        }
    } else if (tid < 132) {                  // scalars
        const int which = tid - 128;         // 0:s2 1:c0 2:c1 3:cntL
        float acc = 0.f;
#pragma unroll 4
        for (int q = 0; q < BPI; ++q) {
            const float v = base[q * PBS + 128 + which];
            if (which == 0 || which == 3) {
                const int L = (int)base[q * PBS + 132];
                if (L >= 1 && L <= 6)
                    atomicAdd(which == 0 ? &comps2[L - 1] : &compcnt[L - 1], v);
            } else acc += v;
        }
        if (which == 1) w[288] += acc;
        if (which == 2) w[289] += acc;
    }
    __syncthreads();

    if (tid < 32) {
#pragma unroll
        for (int kk = 0; kk < 6; ++kk) w[96 + kk * 32 + tid] += comp[kk][tid];
    } else if (tid < 38) {
        const int kk = tid - 32;
        w[297 + kk] += comps2[kk];
        w[291 + kk] += compcnt[kk];
    }
}

// ---- finalize: unchanged (verified absmax = 0) ----
__global__ void scl_final(const float* __restrict__ ws, float* __restrict__ out)
{
    const int lane = threadIdx.x;               // blockDim = 64 (one wave)
    const int n = lane / 6;
    const int k = lane - n * 6;
    const bool active = lane < 48;              // 8 images x 6 components

    float t_cv = 0.f, t_intra = 0.f, t_inter = 0.f, t_inst = 0.f, t_instn = 0.f;
    float t_sbg = 0.f, t_sbgn = 0.f, t_ssc = 0.f, t_sscn = 0.f;

    if (active) {
        const float* w = ws + (size_t)n * WSN;
        const float cnt    = w[291 + k];
        const float s2     = w[297 + k];
        const float subc   = w[288];
        const float scenec = w[289];
        const float bgc    = 262144.f - subc - scenec;   // exact (ints < 2^24)

        float nv = 0.f;
#pragma unroll
        for (int kk = 0; kk < 6; ++kk) nv += (w[291 + kk] >= 20.f) ? 1.f : 0.f;

        const bool comp_big   = cnt >= 20.f;
        const bool item_valid = (bgc >= 20.f) && (nv >= 1.f);
        const bool cv         = comp_big && item_valid;

        const float den  = cnt + 1e-6f;
        const float dsub = subc + 1e-6f;
        const float dbg  = bgc + 1e-6f;
        const float dsc  = scenec + 1e-6f;

        float dot_mS1 = 0.f, dot_mm = 0.f, d2bg = 0.f, d2sub = 0.f;
        for (int c = 0; c < 32; ++c) {
            const float S1 = w[96 + k * 32 + c];
            const float m  = S1 / den;
            dot_mS1 = fmaf(m, S1, dot_mS1);
            dot_mm  = fmaf(m, m, dot_mm);
            const float msub = w[c] / dsub;
            const float mbg  = (w[64 + c] - w[c] - w[32 + c]) / dbg;
            float d = m - mbg;  d2bg  = fmaf(d, d, d2bg);
            d = m - msub;       d2sub = fmaf(d, d, d2sub);
        }
        const float intra_k = (s2 - 2.f * dot_mS1 + cnt * dot_mm) / den;

        if (cv) {
            t_cv = 1.f;
            t_intra = intra_k;
            const float dd = sqrtf(fmaxf(d2bg, 1e-12f));
            const float r  = fmaxf(0.5f - dd, 0.f);
            t_inter = r * r;
        }
        const bool multi = item_valid && (nv > 1.f);
        if (cv && multi) t_inst = d2sub;

        if (k == 0) {                            // per-image terms, once
            if (multi) t_instn = nv;
            const bool bgcond = item_valid && (subc >= 20.f);
            const bool sccond = item_valid && (scenec >= 20.f) && (subc >= 20.f);
            float d2sb = 0.f, d2ss = 0.f;
            for (int c = 0; c < 32; ++c) {
                const float msub = w[c] / dsub;
                const float mbg  = (w[64 + c] - w[c] - w[32 + c]) / dbg;
                const float msc  = w[32 + c] / dsc;
                float a = msub - mbg; d2sb = fmaf(a, a, d2sb);
                float b = msub - msc; d2ss = fmaf(b, b, d2ss);
            }
            if (bgcond) {
                const float dd = sqrtf(fmaxf(d2sb, 1e-12f));
                const float r  = fmaxf(0.5f - dd, 0.f);
                t_sbg = r * r; t_sbgn = 1.f;
            }
            if (sccond) {
                const float dd = sqrtf(fmaxf(d2ss, 1e-12f));
                const float r  = fmaxf(1.0f - dd, 0.f);   // 2*MARGIN
                t_ssc = r * r; t_sscn = 1.f;
            }
        }
    }

#define RED64(x) { x += __shfl_xor(x, 1); x += __shfl_xor(x, 2); x += __shfl_xor(x, 4); \
                   x += __shfl_xor(x, 8); x += __shfl_xor(x, 16); x += __shfl_xor(x, 32); }
    RED64(t_cv) RED64(t_intra) RED64(t_inter) RED64(t_inst) RED64(t_instn)
    RED64(t_sbg) RED64(t_sbgn) RED64(t_ssc) RED64(t_sscn)
#undef RED64

    if (lane == 0) {
        const float total = t_cv;
        auto avg = [](float s, float nn) { return nn > 0.f ? s / fmaxf(nn, 1.f) : 0.f; };
        const float loss = avg(t_intra, total)
                         + 0.4f * avg(t_inter, total)
                         + 0.1f * avg(t_inst, t_instn)
                         + 0.2f * avg(t_sbg, t_sbgn)
                         + 0.5f * avg(t_ssc, t_sscn);
        out[0] = (total > 0.f) ? loss : 0.f;
    }
}

extern "C" void kernel_launch(void* const* d_in, const int* in_sizes, int n_in,
                              void* d_out, int out_size, void* d_ws, size_t ws_size,
                              hipStream_t stream)
{
    (void)in_sizes; (void)n_in; (void)out_size; (void)ws_size;
    const float* color = (const float*)d_in[0];
    const float* gt    = (const float*)d_in[1];
    const float* bin   = (const float*)d_in[2];
    const int*   lab   = (const int*)d_in[3];
    float* stats = (float*)d_ws;
    float* pb    = (float*)((char*)d_ws + PB_OFF);
    float* out   = (float*)d_out;

    hipMemsetAsync(stats, 0, (size_t)NIMG * WSN * sizeof(float), stream);
    hipLaunchKernelGGL(scl_main, dim3(NIMG * BPI), dim3(256), 0, stream,
                       color, gt, bin, lab, stats, pb);
    hipLaunchKernelGGL(scl_reduce, dim3(NIMG), dim3(256), 0, stream, pb, stats);
    hipLaunchKernelGGL(scl_final, dim3(1), dim3(64), 0, stream, stats, out);
}

// Round 8
// 426.612 us; speedup vs baseline: 1.0545x; 1.0192x over previous
//
#include <hip/hip_runtime.h>

// ---------------------------------------------------------------------------
// SubtitleColorConsistencyLoss — MI355X  (v6: copy-like streaming)
// color f32 [8,32,512,512], gt/binary f32 [8,1,512,512], labels i32 -> scalar.
//
// v6: hot kernel = one block per (n, channel, 16-row slab), streaming 32 KB
// CONTIGUOUS color + 8 KB L2-shared codes; 8192 blocks, 8 waves/SIMD.
// No global atomics (unique partial slots); tiny reduce + epilogue.
// d_ws bytes: [0,9728) stats f32[8][304] | 12288 lc[256] | 16384 cntpb[256][8]
//            | 32768 codes u32[2M] | 4M pb f32[8192][8].
// ---------------------------------------------------------------------------

#define NIMG   8
#define NCH    32
#define IMHW   (512 * 512)
#define SLAB   8192                 // pixels per slab (16 rows), 32 slabs/img
#define NSLAB  32
#define WSN    304
// stats: 0 sub[32] | 32 scene[32] | 64 vtot[32] | 96 comp[6][32]
//        288 sub_cnt | 289 scene_cnt | 291 compcnt[6] | 297 comps2[6]
#define LC_OFF    12288
#define CNT_OFF   16384
#define CODES_OFF 32768
#define PB_OFF    (4 * 1024 * 1024)

__device__ __forceinline__ float red64(float x) {
    x += __shfl_xor(x, 1);  x += __shfl_xor(x, 2);  x += __shfl_xor(x, 4);
    x += __shfl_xor(x, 8);  x += __shfl_xor(x, 16); x += __shfl_xor(x, 32);
    return x;
}

// ---- A: codes + per-slab labelmask + count partials (one block/slab) ----
__global__ __launch_bounds__(256) void scl_codes(
    const float* __restrict__ gt, const float* __restrict__ bin,
    const int* __restrict__ lab, unsigned char* __restrict__ lc,
    float* __restrict__ cntpb, unsigned* __restrict__ codes)
{
    __shared__ float ldsc[8];        // c0, c1, ck[6]
    __shared__ int labmask;
    const int tid = threadIdx.x;
    if (tid < 8) ldsc[tid] = 0.f;
    if (tid == 0) labmask = 0;
    __syncthreads();

    const int n = blockIdx.x >> 5;
    const int s = blockIdx.x & 31;
    const int base = n * IMHW + s * SLAB;

    float c0 = 0.f, c1 = 0.f;
    float ck[6] = {0.f, 0.f, 0.f, 0.f, 0.f, 0.f};
    int lm = 0;
#pragma unroll
    for (int i = 0; i < 8; ++i) {
        const int off = i * 1024 + (tid << 2);
        const int p   = base + off;
        const float4 g4 = *reinterpret_cast<const float4*>(gt + p);
        const float4 b4 = *reinterpret_cast<const float4*>(bin + p);
        const int4   l4 = *reinterpret_cast<const int4*>(lab + p);
        const float gg[4] = {g4.x, g4.y, g4.z, g4.w};
        const float bb[4] = {b4.x, b4.y, b4.z, b4.w};
        const int   ll[4] = {l4.x, l4.y, l4.z, l4.w};
        unsigned wrd = 0;
#pragma unroll
        for (int e = 0; e < 4; ++e) {
            const bool sub  = gg[e] > 0.5f;
            const bool text = bb[e] > 0.5f;
            const int  r    = sub ? 0 : (text ? 1 : 2);  // 0=sub 1=scene 2=bg
            unsigned   ul   = (unsigned)ll[e];
            if (ul > 7u) ul = 7u;
            wrd |= ((ul << 2) | (unsigned)r) << (8 * e);
            lm  |= 1 << ul;
            c0  += (r == 0) ? 1.f : 0.f;
            c1  += (r == 1) ? 1.f : 0.f;
#pragma unroll
            for (int kk = 0; kk < 6; ++kk)
                ck[kk] += (ul == (unsigned)(kk + 1)) ? 1.f : 0.f;
        }
        codes[(base >> 2) + i * 256 + tid] = wrd;
    }

    c0 = red64(c0); c1 = red64(c1);
#pragma unroll
    for (int kk = 0; kk < 6; ++kk) ck[kk] = red64(ck[kk]);
    lm |= __shfl_xor(lm, 1);  lm |= __shfl_xor(lm, 2);  lm |= __shfl_xor(lm, 4);
    lm |= __shfl_xor(lm, 8);  lm |= __shfl_xor(lm, 16); lm |= __shfl_xor(lm, 32);
    if ((tid & 63) == 0) {
        atomicAdd(&ldsc[0], c0);
        atomicAdd(&ldsc[1], c1);
#pragma unroll
        for (int kk = 0; kk < 6; ++kk) atomicAdd(&ldsc[2 + kk], ck[kk]);
        atomicOr(&labmask, lm);
    }
    __syncthreads();

    if (tid == 0)
        lc[blockIdx.x] = (unsigned char)((labmask >> 1) & 0x3F);  // labels 1..6
    if (tid < 8)
        cntpb[blockIdx.x * 8 + tid] = ldsc[tid];
}

// ---- B: contiguous per-channel streaming (one block = 32 KB of one plane) ----
__global__ __launch_bounds__(256, 8) void scl_color(
    const float* __restrict__ color, const unsigned char* __restrict__ lc,
    const unsigned* __restrict__ codes, float* __restrict__ pb,
    float* __restrict__ stats)
{
    __shared__ float acc[5];
    const int tid  = threadIdx.x;
    const int lane = tid & 63;
    if (tid < 5) acc[tid] = 0.f;
    __syncthreads();

    const int bid = blockIdx.x;          // = ((n*NSLAB)+sl)*NCH + c
    const int c   = bid & 31;
    const int sl  = (bid >> 5) & 31;
    const int n   = bid >> 10;

    const size_t colbase = ((size_t)(n * NCH + c)) * IMHW + sl * SLAB;
    const int    wbase   = (n * IMHW + sl * SLAB) >> 2;

    const unsigned mask6 = lc[n * NSLAB + sl];
    const int Lc = mask6 ? __ffs(mask6) : 255;   // bit0 = label 1

    float vt = 0.f, s0 = 0.f, s1 = 0.f, aL = 0.f, s2 = 0.f;
#pragma unroll
    for (int i = 0; i < 8; ++i) {
        const int off = i * 1024 + (tid << 2);
        const float4 v4 = *reinterpret_cast<const float4*>(color + colbase + off);
        const unsigned cw = codes[wbase + i * 256 + tid];
        const float vv[4] = {v4.x, v4.y, v4.z, v4.w};
#pragma unroll
        for (int e = 0; e < 4; ++e) {
            const float v = vv[e];
            const int r = (int)((cw >> (8 * e)) & 3u);
            const int l = (int)((cw >> (8 * e + 2)) & 0x3Fu);
            vt += v;
            s0 += (r == 0) ? v : 0.f;
            s1 += (r == 1) ? v : 0.f;
            const float mv = (l == Lc) ? v : 0.f;
            aL += mv;
            s2 = fmaf(mv, mv, s2);
        }
    }

    vt = red64(vt); s0 = red64(s0); s1 = red64(s1);
    aL = red64(aL); s2 = red64(s2);
    if (lane == 0) {                     // 4 wave leaders
        atomicAdd(&acc[0], s0);
        atomicAdd(&acc[1], s1);
        atomicAdd(&acc[2], vt);
        atomicAdd(&acc[3], aL);
        atomicAdd(&acc[4], s2);
    }
    __syncthreads();
    if (tid < 5) pb[(size_t)bid * 8 + tid] = acc[tid];

    // general-data fallback: extra labels in slab (never taken: 16-row slab
    // vs rects >= 35 rows apart); re-stream from L2, rare global atomics.
    unsigned extra = mask6 ? (mask6 & (mask6 - 1)) : 0u;
    while (extra) {
        const int L2 = __ffs(extra); extra &= extra - 1;
        float aX = 0.f, sX = 0.f;
        for (int i = 0; i < 8; ++i) {
            const int off = i * 1024 + (tid << 2);
            const float4 v4 = *reinterpret_cast<const float4*>(color + colbase + off);
            const unsigned cw = codes[wbase + i * 256 + tid];
            const float vv[4] = {v4.x, v4.y, v4.z, v4.w};
#pragma unroll
            for (int e = 0; e < 4; ++e) {
                const int l = (int)((cw >> (8 * e + 2)) & 0x3Fu);
                const float mv = (l == L2) ? vv[e] : 0.f;
                aX += mv;
                sX = fmaf(mv, mv, sX);
            }
        }
        aX = red64(aX); sX = red64(sX);
        if (lane == 0) {                 // 4 wave partials sum correctly
            atomicAdd(&stats[(size_t)n * WSN + 96 + (L2 - 1) * 32 + c], aX);
            atomicAdd(&stats[(size_t)n * WSN + 297 + (L2 - 1)], sX);
        }
    }
}

// ---- reduce: fold partials into stats (one block per image) ----
__global__ __launch_bounds__(64) void scl_reduce(
    const float* __restrict__ pb, const float* __restrict__ cntpb,
    const unsigned char* __restrict__ lc, float* __restrict__ stats)
{
    __shared__ float comp[6][32];
    __shared__ float comps2[6];
    const int tid = threadIdx.x;        // 64 threads
    const int n   = blockIdx.x;
    for (int i = tid; i < 192; i += 64) (&comp[0][0])[i] = 0.f;
    if (tid < 6) comps2[tid] = 0.f;
    __syncthreads();

    float* w = stats + (size_t)n * WSN;

    if (tid < 32) {                     // per-channel sums over 32 slabs
        const int c = tid;
        float a0 = 0.f, a1 = 0.f, a2 = 0.f;
        for (int sl = 0; sl < NSLAB; ++sl) {
            const float* p = pb + ((size_t)((n * NSLAB + sl) * NCH + c)) * 8;
            a0 += p[0]; a1 += p[1]; a2 += p[2];
            const unsigned m = lc[n * NSLAB + sl];
            if (m) {
                const int L = __ffs(m);
                atomicAdd(&comp[L - 1][c], p[3]);
                atomicAdd(&comps2[L - 1], p[4]);
            }
        }
        w[ 0 + c] += a0;
        w[32 + c] += a1;
        w[64 + c] += a2;
    } else if (tid < 40) {              // count partials
        const int j = tid - 32;
        float a = 0.f;
        for (int sl = 0; sl < NSLAB; ++sl)
            a += cntpb[(n * NSLAB + sl) * 8 + j];
        if (j == 0) w[288] += a;
        else if (j == 1) w[289] += a;
        else w[291 + (j - 2)] += a;
    }
    __syncthreads();

    if (tid < 32) {
#pragma unroll
        for (int kk = 0; kk < 6; ++kk) w[96 + kk * 32 + tid] += comp[kk][tid];
    } else if (tid < 38) {
        w[297 + (tid - 32)] += comps2[tid - 32];
    }
}

// ---- finalize: unchanged (verified absmax = 0) ----
__global__ void scl_final(const float* __restrict__ ws, float* __restrict__ out)
{
    const int lane = threadIdx.x;               // blockDim = 64 (one wave)
    const int n = lane / 6;
    const int k = lane - n * 6;
    const bool active = lane < 48;              // 8 images x 6 components

    float t_cv = 0.f, t_intra = 0.f, t_inter = 0.f, t_inst = 0.f, t_instn = 0.f;
    float t_sbg = 0.f, t_sbgn = 0.f, t_ssc = 0.f, t_sscn = 0.f;

    if (active) {
        const float* w = ws + (size_t)n * WSN;
        const float cnt    = w[291 + k];
        const float s2     = w[297 + k];
        const float subc   = w[288];
        const float scenec = w[289];
        const float bgc    = 262144.f - subc - scenec;   // exact (ints < 2^24)

        float nv = 0.f;
#pragma unroll
        for (int kk = 0; kk < 6; ++kk) nv += (w[291 + kk] >= 20.f) ? 1.f : 0.f;

        const bool comp_big   = cnt >= 20.f;
        const bool item_valid = (bgc >= 20.f) && (nv >= 1.f);
        const bool cv         = comp_big && item_valid;

        const float den  = cnt + 1e-6f;
        const float dsub = subc + 1e-6f;
        const float dbg  = bgc + 1e-6f;
        const float dsc  = scenec + 1e-6f;

        float dot_mS1 = 0.f, dot_mm = 0.f, d2bg = 0.f, d2sub = 0.f;
        for (int c = 0; c < 32; ++c) {
            const float S1 = w[96 + k * 32 + c];
            const float m  = S1 / den;
            dot_mS1 = fmaf(m, S1, dot_mS1);
            dot_mm  = fmaf(m, m, dot_mm);
            const float msub = w[c] / dsub;
            const float mbg  = (w[64 + c] - w[c] - w[32 + c]) / dbg;
            float d = m - mbg;  d2bg  = fmaf(d, d, d2bg);
            d = m - msub;       d2sub = fmaf(d, d, d2sub);
        }
        const float intra_k = (s2 - 2.f * dot_mS1 + cnt * dot_mm) / den;

        if (cv) {
            t_cv = 1.f;
            t_intra = intra_k;
            const float dd = sqrtf(fmaxf(d2bg, 1e-12f));
            const float r  = fmaxf(0.5f - dd, 0.f);
            t_inter = r * r;
        }
        const bool multi = item_valid && (nv > 1.f);
        if (cv && multi) t_inst = d2sub;

        if (k == 0) {                            // per-image terms, once
            if (multi) t_instn = nv;
            const bool bgcond = item_valid && (subc >= 20.f);
            const bool sccond = item_valid && (scenec >= 20.f) && (subc >= 20.f);
            float d2sb = 0.f, d2ss = 0.f;
            for (int c = 0; c < 32; ++c) {
                const float msub = w[c] / dsub;
                const float mbg  = (w[64 + c] - w[c] - w[32 + c]) / dbg;
                const float msc  = w[32 + c] / dsc;
                float a = msub - mbg; d2sb = fmaf(a, a, d2sb);
                float b = msub - msc; d2ss = fmaf(b, b, d2ss);
            }
            if (bgcond) {
                const float dd = sqrtf(fmaxf(d2sb, 1e-12f));
                const float r  = fmaxf(0.5f - dd, 0.f);
                t_sbg = r * r; t_sbgn = 1.f;
            }
            if (sccond) {
                const float dd = sqrtf(fmaxf(d2ss, 1e-12f));
                const float r  = fmaxf(1.0f - dd, 0.f);   // 2*MARGIN
                t_ssc = r * r; t_sscn = 1.f;
            }
        }
    }

#define RED64(x) { x += __shfl_xor(x, 1); x += __shfl_xor(x, 2); x += __shfl_xor(x, 4); \
                   x += __shfl_xor(x, 8); x += __shfl_xor(x, 16); x += __shfl_xor(x, 32); }
    RED64(t_cv) RED64(t_intra) RED64(t_inter) RED64(t_inst) RED64(t_instn)
    RED64(t_sbg) RED64(t_sbgn) RED64(t_ssc) RED64(t_sscn)
#undef RED64

    if (lane == 0) {
        const float total = t_cv;
        auto avg = [](float s, float nn) { return nn > 0.f ? s / fmaxf(nn, 1.f) : 0.f; };
        const float loss = avg(t_intra, total)
                         + 0.4f * avg(t_inter, total)
                         + 0.1f * avg(t_inst, t_instn)
                         + 0.2f * avg(t_sbg, t_sbgn)
                         + 0.5f * avg(t_ssc, t_sscn);
        out[0] = (total > 0.f) ? loss : 0.f;
    }
}

extern "C" void kernel_launch(void* const* d_in, const int* in_sizes, int n_in,
                              void* d_out, int out_size, void* d_ws, size_t ws_size,
                              hipStream_t stream)
{
    (void)in_sizes; (void)n_in; (void)out_size; (void)ws_size;
    const float* color = (const float*)d_in[0];
    const float* gt    = (const float*)d_in[1];
    const float* bin   = (const float*)d_in[2];
    const int*   lab   = (const int*)d_in[3];
    float*         stats = (float*)d_ws;
    unsigned char* lc    = (unsigned char*)d_ws + LC_OFF;
    float*         cntpb = (float*)((char*)d_ws + CNT_OFF);
    unsigned*      codes = (unsigned*)((char*)d_ws + CODES_OFF);
    float*         pb    = (float*)((char*)d_ws + PB_OFF);
    float* out = (float*)d_out;

    hipMemsetAsync(stats, 0, (size_t)NIMG * WSN * sizeof(float), stream);
    hipLaunchKernelGGL(scl_codes, dim3(NIMG * NSLAB), dim3(256), 0, stream,
                       gt, bin, lab, lc, cntpb, codes);
    hipLaunchKernelGGL(scl_color, dim3(NIMG * NSLAB * NCH), dim3(256), 0, stream,
                       color, lc, codes, pb, stats);
    hipLaunchKernelGGL(scl_reduce, dim3(NIMG), dim3(64), 0, stream,
                       pb, cntpb, lc, stats);
    hipLaunchKernelGGL(scl_final, dim3(1), dim3(64), 0, stream, stats, out);
}